// Round 4
// baseline (1817.579 us; speedup 1.0000x reference)
//
#include <hip/hip_runtime.h>
#include <hip/hip_bf16.h>
#include <cstdint>
#include <cstddef>

#define NU   8000
#define NI   10000
#define NTOT 18000
#define G    4096
#define KP2  18176      // slots: users 0..8063, items 8064..18175
#define NSL128 142      // 128-slot tiles
#define KT8  142        // 128-byte k-tiles (K = KP2)
#define UT8  63         // user 128-tiles (63*128 = 8064)
#define KP2B 2272       // KP2/8 bit-bytes
#define GB8  512        // G/8 bit-bytes

typedef __attribute__((ext_vector_type(4))) float f32x4;

__device__ __forceinline__ float bfu(unsigned short u){
  return __uint_as_float(((unsigned)u)<<16);
}
__device__ __forceinline__ unsigned short f2b(float f){
  __hip_bfloat16 h = __float2bfloat16(f);
  return __builtin_bit_cast(unsigned short, h);
}
__device__ __forceinline__ unsigned char f2f8(float v){
  int p = __builtin_amdgcn_cvt_pk_fp8_f32(v, 0.f, 0, false);
  return (unsigned char)(p & 0xff);
}
template<int SEL>
__device__ __forceinline__ float f8tof(unsigned int w){
  return __builtin_amdgcn_cvt_f32_fp8((int)w, SEL);
}
__device__ __forceinline__ void async16(void* lds, const void* g){
  __builtin_amdgcn_global_load_lds((const __attribute__((address_space(1))) unsigned int*)g,
                                   (__attribute__((address_space(3))) unsigned int*)lds, 16, 0, 0);
}
__device__ __forceinline__ int slot2n(int s){
  return (s < 8064) ? (s < 8000 ? s : -1) : (s-64 < NTOT ? s-64 : -1);
}
// 4 bits -> dword byte-mask (0xFF per set bit). Exact, no LUT.
__device__ __forceinline__ unsigned int mask4(unsigned int n){
  return ((n*0x00204081u)&0x01010101u)*0xFFu;
}

// ---------------- K1: v projection only + su = Ws-weighted feats sum, sws = sum Ws ----------------
// (q/k eliminated: s[n] = w2.x[n] + c with w2,c derived from su/sws in k_score)
__global__ __launch_bounds__(256) void k_proj(
    const float* __restrict__ feats,
    const float* uWv, const float* ubv, const float* uWs,
    const float* iWv, const float* ibv, const float* iWs,
    unsigned short* __restrict__ vrow, float* __restrict__ suG)
{
  __shared__ unsigned short Wt[2*4096];
  __shared__ float bl[2*64];
  __shared__ float sacc[130];
  const float* mats[2]  = {uWv,iWv};
  const float* bias2[2] = {ubv,ibv};
  int t = threadIdx.x;
  for (int m=0;m<2;m++)
    for (int e=t; e<4096; e+=256){
      int dd = e>>6, jj = e&63;
      Wt[m*4096 + jj*64 + dd] = f2b(mats[m][e]);
    }
  for (int e=t; e<128; e+=256) bl[e] = bias2[e>>6][e&63];
  if (t<130) sacc[t]=0.f;
  __syncthreads();
  int wave=t>>6, lane=t&63;
  int gw = blockIdx.x*4+wave, nw = gridDim.x*4;
  float accU=0.f, accI=0.f, swsU=0.f, swsI=0.f;
  for (int n=gw; n<NTOT; n+=nw){
    int br = (n>=NU);
    const unsigned short* W = Wt + br*4096;
    float x = feats[(size_t)n*64+lane];
    float vd = bl[br*64+lane];
    #pragma unroll 16
    for (int j=0;j<64;j++){
      float xj = __shfl(x, j, 64);
      vd += xj * bfu(W[j*64+lane]);
    }
    vrow[(size_t)n*64+lane] = f2b(vd);
    float wsn = br ? iWs[n-NU] : uWs[n];
    if (br){ accI += wsn*x; swsI += wsn; } else { accU += wsn*x; swsU += wsn; }
  }
  atomicAdd(&sacc[lane], accU);
  atomicAdd(&sacc[64+lane], accI);
  if (lane==0){ atomicAdd(&sacc[128], swsU); atomicAdd(&sacc[129], swsI); }
  __syncthreads();
  if (t<130) atomicAdd(&suG[t], sacc[t]);
}

// ---------------- K2: w2 derivation (redundant per block) + scores + vt8 build (fused from mid) ----------------
__global__ __launch_bounds__(256) void k_score(
    const float* __restrict__ feats, const float* __restrict__ suG,
    const float* uWq, const float* ubq, const float* uWk, const float* ubk, const float* ubs,
    const float* iWq, const float* ibq, const float* iWk, const float* ibk, const float* ibs,
    const unsigned short* __restrict__ vrow,
    float* __restrict__ rfs, unsigned char* __restrict__ rbs, unsigned char* __restrict__ vt8)
{
  __shared__ float suL[130];
  __shared__ float wskL[128];
  __shared__ float w2L[128];
  __shared__ float cL[2];
  __shared__ unsigned short tile[64][65];
  int t=threadIdx.x, wave=t>>6, lane=t&63;
  if (t<130) suL[t]=suG[t];
  __syncthreads();
  // wsk[d] = sum_j su[j]*Wk[d][j] + sws*bk[d]
  if (wave<2){
    const float* Wk = wave? iWk : uWk;
    const float* bk = wave? ibk : ubk;
    const float* su = suL + wave*64;
    float a = suL[128+wave]*bk[lane];
    #pragma unroll 8
    for (int j=0;j<64;j++) a += su[j]*Wk[lane*64+j];
    wskL[wave*64+lane] = a;
  }
  __syncthreads();
  // w2[j] = sum_d wsk[d]*Wq[d][j] ; c = wsk.bq + bs
  if (wave<2){
    const float* Wq = wave? iWq : uWq;
    const float* bq = wave? ibq : ubq;
    const float* wk = wskL + wave*64;
    float a = 0.f;
    #pragma unroll 8
    for (int d=0; d<64; d++) a += wk[d]*Wq[(size_t)d*64+lane];
    w2L[wave*64+lane] = a;
    float cp = wk[lane]*bq[lane];
    #pragma unroll
    for (int m=32;m>=1;m>>=1) cp += __shfl_xor(cp, m, 64);
    if (lane==0) cL[wave] = cp + (wave? ibs[0] : ubs[0]);
  }
  __syncthreads();
  int s0 = blockIdx.x*128;
  int br = (s0>=8064);
  // scores: s[n] = w2 . feats[n] + c
  #pragma unroll 4
  for (int i=0;i<32;i++){
    int slot = s0 + i*4 + wave;
    int n = slot2n(slot);
    float v = 0.f;
    if (n>=0) v = feats[(size_t)n*64+lane] * w2L[br*64+lane];
    #pragma unroll
    for (int m=32;m>=1;m>>=1) v += __shfl_xor(v, m, 64);
    if (lane==0){
      if (n>=0){
        unsigned char b = f2f8(expf(v + cL[br]));
        rbs[slot]=b; rfs[slot]=f8tof<0>((unsigned int)b);
      } else { rbs[slot]=0; rfs[slot]=0.f; }
    }
  }
  // vt8 for this block's two 64-slot tiles (columns outside own side stay memset-zero)
  int dOff = br ? 64 : 0;
  int tc = t&63, tr = t>>6;
  for (int h=0; h<2; h++){
    int sb = s0 + h*64;
    __syncthreads();
    #pragma unroll
    for (int i=0;i<16;i++){
      int row = tr+i*4;
      int n = slot2n(sb+row);
      tile[row][tc] = (n>=0) ? vrow[(size_t)n*64+tc] : (unsigned short)0;
    }
    __syncthreads();
    #pragma unroll
    for (int i=0;i<16;i++){
      int dd = tr+i*4;
      float v = bfu(tile[tc][dd]) * 16.f;
      vt8[(size_t)(dOff+dd)*KP2 + sb+tc] = f2f8(v);
    }
  }
}

// ---------------- K3: ONE pass over H -> bit matrices Wb, Wbt + Z, S2; LAST block computes scales ----------------
__global__ __launch_bounds__(256) void k_buildB(
    const int* __restrict__ H, const float* __restrict__ rfs,
    unsigned char* __restrict__ Wb, unsigned char* __restrict__ Wbt,
    float* __restrict__ Zu, float* __restrict__ Zi,
    float* __restrict__ S2u, float* __restrict__ S2i,
    unsigned int* __restrict__ cntB,
    float* __restrict__ Cu, float* __restrict__ Ci,
    float* __restrict__ cnu, float* __restrict__ cni, float* __restrict__ ninv,
    unsigned char* __restrict__ cn8u, unsigned char* __restrict__ cn8i)
{
  __shared__ __align__(16) unsigned char Bt[128][16];  // bit tile
  __shared__ float rl[128];
  __shared__ float zp[16][128];
  __shared__ float sp[16][128];
  __shared__ unsigned lf;
  int t = threadIdx.x;
  int s0 = blockIdx.x*128, g0 = blockIdx.y*128;
  int isItem = (s0 >= 8064);
  if (t<128){ int n = slot2n(s0+t); rl[t] = (n>=0)? rfs[s0+t] : 0.f; }
  __syncthreads();
  int gb = t&15, rbase = t>>4;
  float za[8]={0.f,0.f,0.f,0.f,0.f,0.f,0.f,0.f};
  float sa[8]={0.f,0.f,0.f,0.f,0.f,0.f,0.f,0.f};
  #pragma unroll
  for (int i=0;i<8;i++){
    int row = rbase + i*16;
    int n = slot2n(s0+row);
    unsigned int b8 = 0;
    if (n>=0){
      const int* hp = H + (size_t)n*G + g0 + gb*8;
      int4 h0 = *(const int4*)hp;
      int4 h1 = *(const int4*)(hp+4);
      float rq = rl[row], rq2 = rq*rq;
      if (h0.x){ b8|=1u;    za[0]+=rq; sa[0]+=rq2; }
      if (h0.y){ b8|=2u;    za[1]+=rq; sa[1]+=rq2; }
      if (h0.z){ b8|=4u;    za[2]+=rq; sa[2]+=rq2; }
      if (h0.w){ b8|=8u;    za[3]+=rq; sa[3]+=rq2; }
      if (h1.x){ b8|=16u;   za[4]+=rq; sa[4]+=rq2; }
      if (h1.y){ b8|=32u;   za[5]+=rq; sa[5]+=rq2; }
      if (h1.z){ b8|=64u;   za[6]+=rq; sa[6]+=rq2; }
      if (h1.w){ b8|=128u;  za[7]+=rq; sa[7]+=rq2; }
    }
    Bt[row][gb] = (unsigned char)b8;
  }
  #pragma unroll
  for (int j=0;j<8;j++){ zp[rbase][gb*8+j]=za[j]; sp[rbase][gb*8+j]=sa[j]; }
  __syncthreads();
  // Wbt rows: 8B/thread
  {
    int row = t>>1, half = t&1;
    *(unsigned long long*)(Wbt + (size_t)(s0+row)*GB8 + (g0>>3) + half*8) =
        *(const unsigned long long*)(&Bt[row][half*8]);
  }
  // Wb transpose: 8 output bytes per thread
  {
    int g = t>>1, sh = t&1;
    int gB = g>>3, gs = g&7;
    unsigned long long ob = 0;
    #pragma unroll
    for (int sb=0; sb<8; sb++){
      int base = (sh*8+sb)*8;
      unsigned int x = 0;
      #pragma unroll
      for (int j=0;j<8;j++) x |= (((unsigned int)(Bt[base+j][gB]) >> gs)&1u) << j;
      ob |= (unsigned long long)x << (sb*8);
    }
    *(unsigned long long*)(Wb + (size_t)(g0+g)*KP2B + (s0>>3) + sh*8) = ob;
  }
  if (t<128){
    float z=0.f, s2=0.f;
    #pragma unroll
    for (int j=0;j<16;j++){ z += zp[j][t]; s2 += sp[j][t]; }
    if (isItem){ atomicAdd(&Zi[g0+t], z); atomicAdd(&S2i[g0+t], s2); }
    else       { atomicAdd(&Zu[g0+t], z); atomicAdd(&S2u[g0+t], s2); }
  }
  // ---- completion-counter fused scales (old k_mid block 0) ----
  __threadfence();
  if (t==0) lf = atomicAdd(cntB, 1u);
  __syncthreads();
  if (lf != (unsigned)(NSL128*32-1)) return;
  __threadfence();
  for (int g=t; g<G; g+=256){
    float zu=Zu[g], zi=Zi[g];
    int fu = !(zu>0.f), fi = !(zi>0.f);
    float cu = fu ? (1.f/(float)NU) : 1.f/zu;
    float ci = fi ? (1.f/(float)NI) : 1.f/zi;
    float nu  = fu ? (1.f/(float)NU) : S2u[g]*cu*cu;
    float ni_ = fi ? (1.f/(float)NI) : S2i[g]*ci*ci;
    float nv = rsqrtf(nu+ni_);
    Cu[g]=cu; Ci[g]=ci; ninv[g]=nv; cnu[g]=cu*nv; cni[g]=ci*nv;
    cn8u[g] = f2f8(cu*nv*64.f);
    cn8i[g] = f2f8(ci*nv*64.f);
    // never-taken degenerate patch (all-masked group): set all valid bits
    if (fu){
      for (int k=0;k<1000;k++) Wb[(size_t)g*KP2B+k]=0xFF;
      for (int k=0;k<NU;k++)
        atomicOr((unsigned*)Wbt + (((size_t)k*GB8 + (g>>3))>>2), 1u<<((g&7) + 8*((g>>3)&3)));
    }
    if (fi){
      for (int k=1008;k<2258;k++) Wb[(size_t)g*KP2B+k]=0xFF;
      for (int k=8064;k<18064;k++)
        atomicOr((unsigned*)Wbt + (((size_t)k*GB8 + (g>>3))>>2), 1u<<((g&7) + 8*((g>>3)&3)));
    }
  }
}

// ---------------- K6: fp8 GEMM with bit-expanded W operand, split-K; fused last-block reductions ----------------
// MODE 0: gfsl[z] = expand(Wb).vt8^T, grid (32,1,16); last z-block per I does gfpost (gf + gfsT2_8)
// MODE 1: tmpsl[z] = gfsT2_8.expand(Wbt)^T + u-row, grid (1,142,4); last z-block per J does red1 (tmpT8 + u8)
// MODE 2: msgsl[z] = expand(Wb).tmpT8^T ; degsl = expand(Wb).u8, grid (32,1,16); reduce fused in k_final
template<int MODE>
__global__ __launch_bounds__(256) void k_gemm(
    const unsigned char* __restrict__ A, const unsigned char* __restrict__ B,
    float* __restrict__ Cs, float* __restrict__ degsl,
    const unsigned char* __restrict__ u8,
    const unsigned char* __restrict__ cn8u, const unsigned char* __restrict__ cn8i,
    float* __restrict__ uslice, const unsigned char* __restrict__ rbsg,
    unsigned int* __restrict__ cnt,
    const float* __restrict__ Cu, const float* __restrict__ Ci, const float* __restrict__ ninv,
    float* __restrict__ gf, unsigned char* __restrict__ gfsT2_8,
    unsigned char* __restrict__ tmpT8o, unsigned char* __restrict__ u8o,
    long ldF, long ldc)
{
  __shared__ __align__(16) unsigned char BufF[2][16384];  // fp8 operand tile (B for 0/2, A for 1)
  __shared__ __align__(16) unsigned char BufB[2][2048];   // bit tile [128][16]
  __shared__ __align__(16) unsigned char AuxR[2][1024];   // rbs k-chunk (MODE0/2)
  __shared__ unsigned int RowDw[128];                     // per-row value splat (MODE1)
  __shared__ unsigned lfs;
  int t=threadIdx.x, wave=t>>6, lane=t&63;
  int I=blockIdx.x, J=blockIdx.y, z=blockIdx.z;
  int kt0=0, ktn=0;
  if (MODE==0){ kt0 = z*9; ktn = min(9, KT8-kt0); }
  else if (MODE==1){ kt0 = z*8; ktn = 8; }
  else {
    if (z<8){ kt0 = z*8;             ktn = min(8, UT8-kt0); }
    else    { kt0 = UT8 + (z-8)*10;  ktn = min(10, KT8-kt0); }
  }
  f32x4 acc[4][4];
  #pragma unroll
  for (int mi=0;mi<4;mi++)
    #pragma unroll
    for (int ni=0;ni<4;ni++){
      acc[mi][ni][0]=0.f; acc[mi][ni][1]=0.f; acc[mi][ni][2]=0.f; acc[mi][ni][3]=0.f;
    }
  f32x4 accd[4];
  if (MODE==2){
    #pragma unroll
    for (int mi=0;mi<4;mi++){ accd[mi][0]=0.f; accd[mi][1]=0.f; accd[mi][2]=0.f; accd[mi][3]=0.f; }
  }
  f32x4 accu[4];
  if (MODE==1){
    #pragma unroll
    for (int ni=0;ni<4;ni++){ accu[ni][0]=0.f; accu[ni][1]=0.f; accu[ni][2]=0.f; accu[ni][3]=0.f; }
  }
  int l7 = lane&7, q4 = lane>>4, cl15 = lane&15;
  int rowOff = wave*8 + (lane>>3);
  int cchunk = (lane&7) ^ ((lane>>3)&7);
  long aRow0 = (MODE==1) ? ((J>=UT8)?128:0) : 0;
  const unsigned char* Fbase;
  const unsigned char* Bitbase;
  if (MODE==1){ Fbase = A + aRow0*ldF + (long)cchunk*16; Bitbase = B + (long)J*128*GB8; }
  else        { Fbase = B + (long)cchunk*16;             Bitbase = A + (long)I*128*KP2B; }
  const unsigned char* cnrow = (MODE==1) ? ((J>=UT8) ? cn8i : cn8u) : nullptr;
  int mrow0 = (wave&1)*64, nrow0 = (wave>>1)*64;

  if (MODE==1 && t<128) RowDw[t] = 0x01010101u * (unsigned int)rbsg[(size_t)J*128 + t];

  auto STAGE = [&](int buf, int kt){
    long k0 = (long)kt*128;
    #pragma unroll
    for (int rr=0; rr<4; rr++)
      async16(BufF[buf] + wave*1024 + rr*4096, Fbase + (long)(rr*32 + rowOff)*ldF + k0);
    if (wave<2)
      async16(BufB[buf] + wave*1024, Bitbase + (long)(wave*64+lane)*(MODE==1?GB8:KP2B) + (long)kt*16);
    if (MODE!=1 && wave==2)
      async16(AuxR[buf], rbsg + (long)kt*128 + (long)(lane&7)*16);
  };

  STAGE(0, kt0);
  __syncthreads();

  for (int kt=kt0; kt<kt0+ktn; ++kt){
    int cur = (kt - kt0) & 1;
    if (kt+1 < kt0+ktn) STAGE(cur^1, kt+1);
    const unsigned char* Fb = BufF[cur];
    const unsigned char* Bb = BufB[cur];
    #pragma unroll
    for (int kk=0; kk<4; kk++){
      int xoff = (((kk*2 + (q4>>1)) ^ l7) << 4) + ((q4&1)<<3);
      int kb = kk*4 + q4;
      long af[4], bf[4];
      if (MODE==1){
        #pragma unroll
        for (int mi=0;mi<4;mi++)
          af[mi] = *(const long*)(Fb + (mrow0 + mi*16 + cl15)*128 + xoff);
        #pragma unroll
        for (int ni=0;ni<4;ni++){
          int row = nrow0 + ni*16 + cl15;
          unsigned int bb = Bb[row*16 + kb];
          unsigned int sp = RowDw[row];
          unsigned int lo = mask4(bb&15u)&sp, hi = mask4(bb>>4)&sp;
          bf[ni] = (long)(((unsigned long long)hi<<32)|(unsigned long long)lo);
        }
      } else {
        unsigned long long rdw = *(const unsigned long long*)(AuxR[cur] + kb*8);
        unsigned int rlo = (unsigned int)rdw, rhi = (unsigned int)(rdw>>32);
        #pragma unroll
        for (int mi=0;mi<4;mi++){
          unsigned int bb = Bb[(mrow0 + mi*16 + cl15)*16 + kb];
          unsigned int lo = mask4(bb&15u)&rlo, hi = mask4(bb>>4)&rhi;
          af[mi] = (long)(((unsigned long long)hi<<32)|(unsigned long long)lo);
        }
        #pragma unroll
        for (int ni=0;ni<4;ni++)
          bf[ni] = *(const long*)(Fb + (nrow0 + ni*16 + cl15)*128 + xoff);
      }
      #pragma unroll
      for (int mi=0;mi<4;mi++)
        #pragma unroll
        for (int ni=0;ni<4;ni++)
          acc[mi][ni] = __builtin_amdgcn_mfma_f32_16x16x32_fp8_fp8(af[mi], bf[ni], acc[mi][ni], 0,0,0);
      if (MODE==2){
        long bu = 0;
        if (cl15==0) bu = *(const long*)(u8 + (size_t)kt*128 + kk*32 + q4*8);
        #pragma unroll
        for (int mi=0;mi<4;mi++)
          accd[mi] = __builtin_amdgcn_mfma_f32_16x16x32_fp8_fp8(af[mi], bu, accd[mi], 0,0,0);
      }
      if (MODE==1){
        long au = 0;
        if (cl15==0) au = *(const long*)(cnrow + (size_t)kt*128 + kk*32 + q4*8);
        #pragma unroll
        for (int ni=0;ni<4;ni++)
          accu[ni] = __builtin_amdgcn_mfma_f32_16x16x32_fp8_fp8(au, bf[ni], accu[ni], 0,0,0);
      }
    }
    __syncthreads();
  }
  int cq = lane>>4, cl = lane&15;
  float* slice = (MODE==1) ? (Cs + (size_t)z*128*KP2) : (Cs + (size_t)z*G*128);
  #pragma unroll
  for (int mi=0;mi<4;mi++)
    #pragma unroll
    for (int ni=0;ni<4;ni++)
      #pragma unroll
      for (int rg=0;rg<4;rg++){
        int gi = (MODE==1 ? 0 : I*128) + mrow0 + mi*16 + cq*4 + rg;
        int hi = J*128 + nrow0 + ni*16 + cl;
        slice[(size_t)gi*ldc + hi] = acc[mi][ni][rg];
      }
  if (MODE==2 && (wave>>1)==0 && cl15==0){
    #pragma unroll
    for (int mi=0;mi<4;mi++)
      #pragma unroll
      for (int rg=0;rg<4;rg++){
        int gi = I*128 + mrow0 + mi*16 + cq*4 + rg;
        degsl[(size_t)z*G + gi] = accd[mi][rg];
      }
  }
  if (MODE==1 && (wave&1)==0 && q4==0){
    #pragma unroll
    for (int ni=0;ni<4;ni++){
      int si = J*128 + nrow0 + ni*16 + cl15;
      uslice[(size_t)z*KP2 + si] = accu[ni][0];
    }
  }

  // ---- fused split-K reductions (last z-block per output tile) ----
  if (MODE==0){
    __threadfence();
    if (t==0) lfs = atomicAdd(cnt+I, 1u);
    __syncthreads();
    if (lfs != 15u) return;
    __threadfence();
    float (*ftile)[65] = (float(*)[65])(&BufF[0][0]);   // 16.6 KB scratch (spans BufF[0..1])
    int tc=t&63, tr=t>>6;
    for (int gh=0; gh<2; gh++){
      int g0 = I*128 + gh*64;
      for (int dh=0; dh<2; dh++){
        int d0 = dh*64;
        const float* Cd = dh ? Ci : Cu;   // gf columns 64..127 are item-derived
        __syncthreads();
        #pragma unroll
        for (int i=0;i<16;i++){
          int rr=tr+i*4;
          size_t off = (size_t)(g0+rr)*128 + d0+tc;
          float s = 0.f;
          #pragma unroll
          for (int zz=0; zz<16; zz++) s += Cs[(size_t)zz*G*128 + off];
          float gfv = s * Cd[g0+rr] * 0.0625f;
          gf[off] = gfv;
          ftile[rr][tc] = gfv * ninv[g0+rr];
        }
        __syncthreads();
        #pragma unroll
        for (int i=0;i<16;i++){
          int dd=tr+i*4;
          float v = ftile[tc][dd] * 64.f;
          int g = g0+tc;
          gfsT2_8[(size_t)(d0+dd)*G + g]     = f2f8(v*Cu[g]);
          gfsT2_8[(size_t)(128+d0+dd)*G + g] = f2f8(v*Ci[g]);
        }
      }
    }
  }
  if (MODE==1){
    __threadfence();
    if (t==0) lfs = atomicAdd(cnt+J, 1u);
    __syncthreads();
    if (lfs != 3u) return;
    __threadfence();
    #pragma unroll
    for (int i=0;i<16;i++){
      int idx = i*256 + t;
      int d = idx>>5;
      int cq2 = (idx&31)*4;
      size_t off = (size_t)d*KP2 + J*128 + cq2;
      f32x4 s = *(const f32x4*)(Cs + off);
      #pragma unroll
      for (int zz=1; zz<4; zz++){
        f32x4 v = *(const f32x4*)(Cs + (size_t)zz*128*KP2 + off);
        s[0]+=v[0]; s[1]+=v[1]; s[2]+=v[2]; s[3]+=v[3];
      }
      uchar4 pk;
      pk.x=f2f8(s[0]); pk.y=f2f8(s[1]); pk.z=f2f8(s[2]); pk.w=f2f8(s[3]);
      *(uchar4*)(tmpT8o + off) = pk;
    }
    if (t<128){
      int si = J*128 + t;
      float s = 0.f;
      #pragma unroll
      for (int zz=0; zz<4; zz++) s += uslice[(size_t)zz*KP2 + si];
      u8o[si] = f2f8(s*0.015625f);
    }
  }
}

// ---------------- K9 (absorbs red2): deg + msg-reduce + out = sigmoid(agg @ gW^T + gb) ----------------
__global__ __launch_bounds__(256) void k_final(const float* __restrict__ gf, const float* __restrict__ msgsl,
    const float* __restrict__ degsl, const float* __restrict__ cnu, const float* __restrict__ cni,
    const float* __restrict__ gW, const float* __restrict__ gb, float* __restrict__ out)
{
  __shared__ float Wl[64*129];
  __shared__ float aggL[4][128];
  __shared__ float gbL[64];
  __shared__ float degL[4];
  int t=threadIdx.x;
  for (int e=t; e<8192; e+=256){ int o=e>>7, dd=e&127; Wl[o*129+dd] = gW[e]; }
  if (t<64) gbL[t] = gb[t];
  int g0 = blockIdx.x*4;
  if (t<4){
    int g = g0+t;
    float su=0.f, si=0.f;
    #pragma unroll
    for (int z=0;z<8;z++) su += degsl[(size_t)z*G + g];
    #pragma unroll
    for (int z=8;z<16;z++) si += degsl[(size_t)z*G + g];
    degL[t] = cnu[g]*su + cni[g]*si;
  }
  __syncthreads();
  for (int e=t; e<512; e+=256){
    int gl=e>>7, dd=e&127; int g=g0+gl;
    size_t off = (size_t)g*128 + dd;
    float su=0.f, si=0.f;
    #pragma unroll
    for (int z=0;z<8;z++)  su += msgsl[(size_t)z*G*128 + off];
    #pragma unroll
    for (int z=8;z<16;z++) si += msgsl[(size_t)z*G*128 + off];
    float mv = (cnu[g]*su + cni[g]*si)*0.015625f;
    float dv = degL[gl];
    float hn = dv>0.f ? mv/dv : 0.f;
    aggL[gl][dd] = 0.8f*gf[off] + 0.2f*hn;
  }
  __syncthreads();
  int gl = t>>6, o = t&63;
  float s = gbL[o];
  #pragma unroll
  for (int dd=0; dd<128; dd++) s += aggL[gl][dd]*Wl[o*129+dd];
  out[(size_t)(g0+gl)*64 + o] = 1.f/(1.f+expf(-s));
}

extern "C" void kernel_launch(void* const* d_in, const int* in_sizes, int n_in,
                              void* d_out, int out_size, void* d_ws, size_t ws_size,
                              hipStream_t stream)
{
  (void)in_sizes; (void)n_in; (void)out_size; (void)ws_size;
  const int* H = (const int*)d_in[0];
  const float* feats = (const float*)d_in[1];
  const float* uWq=(const float*)d_in[3];
  const float* ubq=(const float*)d_in[4];
  const float* uWk=(const float*)d_in[5];
  const float* ubk=(const float*)d_in[6];
  const float* uWv=(const float*)d_in[7];
  const float* ubv=(const float*)d_in[8];
  const float* uWs=(const float*)d_in[9];
  const float* ubs=(const float*)d_in[10];
  const float* iWq=(const float*)d_in[11];
  const float* ibq=(const float*)d_in[12];
  const float* iWk=(const float*)d_in[13];
  const float* ibk=(const float*)d_in[14];
  const float* iWv=(const float*)d_in[15];
  const float* ibv=(const float*)d_in[16];
  const float* iWs=(const float*)d_in[17];
  const float* ibs=(const float*)d_in[18];
  const float* gW =(const float*)d_in[19];
  const float* gb =(const float*)d_in[20];
  float* out = (float*)d_out;

  char* p = (char*)d_ws;
  auto alloc=[&](size_t b)->void*{ void* r=(void*)p; p += (b+255)&~(size_t)255; return r; };
  // --- zero region (single small memset) ---
  char* zbase = p;
  float* suG  = (float*)alloc(130*4);
  float* Zu   = (float*)alloc(G*4);
  float* Zi   = (float*)alloc(G*4);
  float* S2u  = (float*)alloc(G*4);
  float* S2i  = (float*)alloc(G*4);
  unsigned int* cnt0 = (unsigned int*)alloc(32*4);
  unsigned int* cnt1 = (unsigned int*)alloc(142*4);
  unsigned int* cntB = (unsigned int*)alloc(4);
  unsigned char* vt8 = (unsigned char*)alloc((size_t)128*KP2);
  size_t zlen = (size_t)(p - zbase);
  // --- non-zeroed ---
  unsigned char* Wb    = (unsigned char*)alloc((size_t)G*KP2B);
  unsigned char* Wbt   = (unsigned char*)alloc((size_t)KP2*GB8);
  unsigned char* tmpT8 = (unsigned char*)alloc((size_t)128*KP2);
  unsigned char* gfsT2_8=(unsigned char*)alloc((size_t)256*G);
  // union slice buffer: gfsl (16 x G x 128 f32) / tmpsl (4 x 128 x KP2 f32) / msgsl (16 x G x 128 f32)
  float* slb  = (float*)alloc((size_t)4*128*KP2*4);
  float* uslice=(float*)alloc((size_t)4*KP2*4);
  float* degsl= (float*)alloc((size_t)16*G*4);
  float* gf   = (float*)alloc((size_t)G*128*4);
  unsigned short* vrow=(unsigned short*)alloc((size_t)NTOT*64*2);
  float* rfs  = (float*)alloc((size_t)KP2*4);
  unsigned char* rbs = (unsigned char*)alloc((size_t)KP2);
  float* Cu   = (float*)alloc(G*4);
  float* Ci   = (float*)alloc(G*4);
  float* cnu  = (float*)alloc(G*4);
  float* cni  = (float*)alloc(G*4);
  float* ninv = (float*)alloc(G*4);
  unsigned char* cn8u = (unsigned char*)alloc(G);
  unsigned char* cn8i = (unsigned char*)alloc(G);
  unsigned char* u8 = (unsigned char*)alloc((size_t)KP2);

  (void)hipMemsetAsync(zbase, 0, zlen, stream);

  k_proj<<<256,256,0,stream>>>(feats, uWv,ubv,uWs, iWv,ibv,iWs, vrow, suG);
  k_score<<<KP2/128,256,0,stream>>>(feats, suG, uWq,ubq,uWk,ubk,ubs,
                                    iWq,ibq,iWk,ibk,ibs, vrow, rfs, rbs, vt8);
  k_buildB<<<dim3(NSL128,32),256,0,stream>>>(H, rfs, Wb, Wbt, Zu, Zi, S2u, S2i,
                                             cntB, Cu, Ci, cnu, cni, ninv, cn8u, cn8i);
  // gf slices + fused gfpost in last z-block per I
  k_gemm<0><<<dim3(32,1,16),256,0,stream>>>(Wb, vt8, slb, nullptr, nullptr, nullptr, nullptr, nullptr,
                                            rbs, cnt0, Cu, Ci, ninv, gf, gfsT2_8, nullptr, nullptr,
                                            (long)KP2, 128);
  // tmp slices (+ fused u-row) + fused red1 in last z-block per J
  k_gemm<1><<<dim3(1,KT8,4),256,0,stream>>>(gfsT2_8, Wbt, slb, nullptr, nullptr, cn8u, cn8i, uslice,
                                            rbs, cnt1, nullptr, nullptr, nullptr, nullptr, nullptr,
                                            tmpT8, u8, (long)G, (long)KP2);
  // msg/deg slices; reduce fused into k_final
  k_gemm<2><<<dim3(32,1,16),256,0,stream>>>(Wb, tmpT8, slb, degsl, u8, nullptr, nullptr, nullptr,
                                            rbs, nullptr, nullptr, nullptr, nullptr, nullptr, nullptr,
                                            nullptr, nullptr, (long)KP2, 128);
  k_final<<<G/4,256,0,stream>>>(gf, slb, degsl, cnu, cni, gW, gb, out);
}

// Round 6
// 667.498 us; speedup vs baseline: 2.7230x; 2.7230x over previous
//
#include <hip/hip_runtime.h>
#include <hip/hip_bf16.h>
#include <cstdint>
#include <cstddef>

#define NU   8000
#define NI   10000
#define NTOT 18000
#define G    4096
#define KP2  18176      // slots: users 0..8063, items 8064..18175
#define NSL128 142      // 128-slot tiles
#define KT8  142        // 128-byte k-tiles (K = KP2)
#define UT8  63         // user 128-tiles (63*128 = 8064)
#define KP2B 2272       // KP2/8 bit-bytes
#define GB8  512        // G/8 bit-bytes

typedef __attribute__((ext_vector_type(4))) float f32x4;

__device__ __forceinline__ float bfu(unsigned short u){
  return __uint_as_float(((unsigned)u)<<16);
}
__device__ __forceinline__ unsigned short f2b(float f){
  __hip_bfloat16 h = __float2bfloat16(f);
  return __builtin_bit_cast(unsigned short, h);
}
__device__ __forceinline__ unsigned char f2f8(float v){
  int p = __builtin_amdgcn_cvt_pk_fp8_f32(v, 0.f, 0, false);
  return (unsigned char)(p & 0xff);
}
template<int SEL>
__device__ __forceinline__ float f8tof(unsigned int w){
  return __builtin_amdgcn_cvt_f32_fp8((int)w, SEL);
}
__device__ __forceinline__ void async16(void* lds, const void* g){
  __builtin_amdgcn_global_load_lds((const __attribute__((address_space(1))) unsigned int*)g,
                                   (__attribute__((address_space(3))) unsigned int*)lds, 16, 0, 0);
}
__device__ __forceinline__ int slot2n(int s){
  return (s < 8064) ? (s < 8000 ? s : -1) : (s-64 < NTOT ? s-64 : -1);
}
// 4 bits -> dword byte-mask (0xFF per set bit). Exact, no LUT.
__device__ __forceinline__ unsigned int mask4(unsigned int n){
  return ((n*0x00204081u)&0x01010101u)*0xFFu;
}

// ---------------- K1: v projection only + su = Ws-weighted feats sum, sws = sum Ws ----------------
// (q/k eliminated: s[n] = w2.x[n] + c with w2,c derived from su/sws in k_score)
__global__ __launch_bounds__(256) void k_proj(
    const float* __restrict__ feats,
    const float* uWv, const float* ubv, const float* uWs,
    const float* iWv, const float* ibv, const float* iWs,
    unsigned short* __restrict__ vrow, float* __restrict__ suG)
{
  __shared__ unsigned short Wt[2*4096];
  __shared__ float bl[2*64];
  __shared__ float sacc[130];
  const float* mats[2]  = {uWv,iWv};
  const float* bias2[2] = {ubv,ibv};
  int t = threadIdx.x;
  for (int m=0;m<2;m++)
    for (int e=t; e<4096; e+=256){
      int dd = e>>6, jj = e&63;
      Wt[m*4096 + jj*64 + dd] = f2b(mats[m][e]);
    }
  for (int e=t; e<128; e+=256) bl[e] = bias2[e>>6][e&63];
  if (t<130) sacc[t]=0.f;
  __syncthreads();
  int wave=t>>6, lane=t&63;
  int gw = blockIdx.x*4+wave, nw = gridDim.x*4;
  float accU=0.f, accI=0.f, swsU=0.f, swsI=0.f;
  for (int n=gw; n<NTOT; n+=nw){
    int br = (n>=NU);
    const unsigned short* W = Wt + br*4096;
    float x = feats[(size_t)n*64+lane];
    float vd = bl[br*64+lane];
    #pragma unroll 16
    for (int j=0;j<64;j++){
      float xj = __shfl(x, j, 64);
      vd += xj * bfu(W[j*64+lane]);
    }
    vrow[(size_t)n*64+lane] = f2b(vd);
    float wsn = br ? iWs[n-NU] : uWs[n];
    if (br){ accI += wsn*x; swsI += wsn; } else { accU += wsn*x; swsU += wsn; }
  }
  atomicAdd(&sacc[lane], accU);
  atomicAdd(&sacc[64+lane], accI);
  if (lane==0){ atomicAdd(&sacc[128], swsU); atomicAdd(&sacc[129], swsI); }
  __syncthreads();
  if (t<130) atomicAdd(&suG[t], sacc[t]);
}

// ---------------- K2: w2 derivation (redundant per block) + scores + vt8 build ----------------
__global__ __launch_bounds__(256) void k_score(
    const float* __restrict__ feats, const float* __restrict__ suG,
    const float* uWq, const float* ubq, const float* uWk, const float* ubk, const float* ubs,
    const float* iWq, const float* ibq, const float* iWk, const float* ibk, const float* ibs,
    const unsigned short* __restrict__ vrow,
    float* __restrict__ rfs, unsigned char* __restrict__ rbs, unsigned char* __restrict__ vt8)
{
  __shared__ float suL[130];
  __shared__ float wskL[128];
  __shared__ float w2L[128];
  __shared__ float cL[2];
  __shared__ unsigned short tile[64][65];
  int t=threadIdx.x, wave=t>>6, lane=t&63;
  if (t<130) suL[t]=suG[t];
  __syncthreads();
  // wsk[d] = sum_j su[j]*Wk[d][j] + sws*bk[d]
  if (wave<2){
    const float* Wk = wave? iWk : uWk;
    const float* bk = wave? ibk : ubk;
    const float* su = suL + wave*64;
    float a = suL[128+wave]*bk[lane];
    #pragma unroll 8
    for (int j=0;j<64;j++) a += su[j]*Wk[lane*64+j];
    wskL[wave*64+lane] = a;
  }
  __syncthreads();
  // w2[j] = sum_d wsk[d]*Wq[d][j] ; c = wsk.bq + bs
  if (wave<2){
    const float* Wq = wave? iWq : uWq;
    const float* bq = wave? ibq : ubq;
    const float* wk = wskL + wave*64;
    float a = 0.f;
    #pragma unroll 8
    for (int d=0; d<64; d++) a += wk[d]*Wq[(size_t)d*64+lane];
    w2L[wave*64+lane] = a;
    float cp = wk[lane]*bq[lane];
    #pragma unroll
    for (int m=32;m>=1;m>>=1) cp += __shfl_xor(cp, m, 64);
    if (lane==0) cL[wave] = cp + (wave? ibs[0] : ubs[0]);
  }
  __syncthreads();
  int s0 = blockIdx.x*128;
  int br = (s0>=8064);
  // scores: s[n] = w2 . feats[n] + c
  #pragma unroll 4
  for (int i=0;i<32;i++){
    int slot = s0 + i*4 + wave;
    int n = slot2n(slot);
    float v = 0.f;
    if (n>=0) v = feats[(size_t)n*64+lane] * w2L[br*64+lane];
    #pragma unroll
    for (int m=32;m>=1;m>>=1) v += __shfl_xor(v, m, 64);
    if (lane==0){
      if (n>=0){
        unsigned char b = f2f8(expf(v + cL[br]));
        rbs[slot]=b; rfs[slot]=f8tof<0>((unsigned int)b);
      } else { rbs[slot]=0; rfs[slot]=0.f; }
    }
  }
  // vt8 for this block's two 64-slot tiles (columns outside own side stay memset-zero)
  int dOff = br ? 64 : 0;
  int tc = t&63, tr = t>>6;
  for (int h=0; h<2; h++){
    int sb = s0 + h*64;
    __syncthreads();
    #pragma unroll
    for (int i=0;i<16;i++){
      int row = tr+i*4;
      int n = slot2n(sb+row);
      tile[row][tc] = (n>=0) ? vrow[(size_t)n*64+tc] : (unsigned short)0;
    }
    __syncthreads();
    #pragma unroll
    for (int i=0;i<16;i++){
      int dd = tr+i*4;
      float v = bfu(tile[tc][dd]) * 16.f;
      vt8[(size_t)(dOff+dd)*KP2 + sb+tc] = f2f8(v);
    }
  }
}

// ---------------- K3: ONE pass over H -> bit matrices Wb, Wbt + Z, S2 (NO fence, NO tail) ----------------
__global__ __launch_bounds__(256) void k_buildB(
    const int* __restrict__ H, const float* __restrict__ rfs,
    unsigned char* __restrict__ Wb, unsigned char* __restrict__ Wbt,
    float* __restrict__ Zu, float* __restrict__ Zi,
    float* __restrict__ S2u, float* __restrict__ S2i)
{
  __shared__ __align__(16) unsigned char Bt[128][16];  // bit tile
  __shared__ float rl[128];
  __shared__ float zp[16][128];
  __shared__ float sp[16][128];
  int t = threadIdx.x;
  int s0 = blockIdx.x*128, g0 = blockIdx.y*128;
  int isItem = (s0 >= 8064);
  if (t<128){ int n = slot2n(s0+t); rl[t] = (n>=0)? rfs[s0+t] : 0.f; }
  __syncthreads();
  int gb = t&15, rbase = t>>4;
  float za[8]={0.f,0.f,0.f,0.f,0.f,0.f,0.f,0.f};
  float sa[8]={0.f,0.f,0.f,0.f,0.f,0.f,0.f,0.f};
  #pragma unroll
  for (int i=0;i<8;i++){
    int row = rbase + i*16;
    int n = slot2n(s0+row);
    unsigned int b8 = 0;
    if (n>=0){
      const int* hp = H + (size_t)n*G + g0 + gb*8;
      int4 h0 = *(const int4*)hp;
      int4 h1 = *(const int4*)(hp+4);
      float rq = rl[row], rq2 = rq*rq;
      if (h0.x){ b8|=1u;    za[0]+=rq; sa[0]+=rq2; }
      if (h0.y){ b8|=2u;    za[1]+=rq; sa[1]+=rq2; }
      if (h0.z){ b8|=4u;    za[2]+=rq; sa[2]+=rq2; }
      if (h0.w){ b8|=8u;    za[3]+=rq; sa[3]+=rq2; }
      if (h1.x){ b8|=16u;   za[4]+=rq; sa[4]+=rq2; }
      if (h1.y){ b8|=32u;   za[5]+=rq; sa[5]+=rq2; }
      if (h1.z){ b8|=64u;   za[6]+=rq; sa[6]+=rq2; }
      if (h1.w){ b8|=128u;  za[7]+=rq; sa[7]+=rq2; }
    }
    Bt[row][gb] = (unsigned char)b8;
  }
  #pragma unroll
  for (int j=0;j<8;j++){ zp[rbase][gb*8+j]=za[j]; sp[rbase][gb*8+j]=sa[j]; }
  __syncthreads();
  // Wbt rows: 8B/thread
  {
    int row = t>>1, half = t&1;
    *(unsigned long long*)(Wbt + (size_t)(s0+row)*GB8 + (g0>>3) + half*8) =
        *(const unsigned long long*)(&Bt[row][half*8]);
  }
  // Wb transpose: 8 output bytes per thread
  {
    int g = t>>1, sh = t&1;
    int gB = g>>3, gs = g&7;
    unsigned long long ob = 0;
    #pragma unroll
    for (int sb=0; sb<8; sb++){
      int base = (sh*8+sb)*8;
      unsigned int x = 0;
      #pragma unroll
      for (int j=0;j<8;j++) x |= (((unsigned int)(Bt[base+j][gB]) >> gs)&1u) << j;
      ob |= (unsigned long long)x << (sb*8);
    }
    *(unsigned long long*)(Wb + (size_t)(g0+g)*KP2B + (s0>>3) + sh*8) = ob;
  }
  if (t<128){
    float z=0.f, s2=0.f;
    #pragma unroll
    for (int j=0;j<16;j++){ z += zp[j][t]; s2 += sp[j][t]; }
    if (isItem){ atomicAdd(&Zi[g0+t], z); atomicAdd(&S2i[g0+t], s2); }
    else       { atomicAdd(&Zu[g0+t], z); atomicAdd(&S2u[g0+t], s2); }
  }
}

// ---------------- K4: scales only (tiny dispatch; old k_mid block 0) ----------------
__global__ __launch_bounds__(256) void k_scales(
    const float* __restrict__ Zu, const float* __restrict__ Zi,
    const float* __restrict__ S2u, const float* __restrict__ S2i,
    float* __restrict__ Cu, float* __restrict__ Ci,
    float* __restrict__ cnu, float* __restrict__ cni, float* __restrict__ ninv,
    unsigned char* __restrict__ cn8u, unsigned char* __restrict__ cn8i,
    unsigned char* __restrict__ Wb, unsigned char* __restrict__ Wbt)
{
  int g = blockIdx.x*256 + threadIdx.x;
  if (g >= G) return;
  float zu=Zu[g], zi=Zi[g];
  int fu = !(zu>0.f), fi = !(zi>0.f);
  float cu = fu ? (1.f/(float)NU) : 1.f/zu;
  float ci = fi ? (1.f/(float)NI) : 1.f/zi;
  float nu  = fu ? (1.f/(float)NU) : S2u[g]*cu*cu;
  float ni_ = fi ? (1.f/(float)NI) : S2i[g]*ci*ci;
  float nv = rsqrtf(nu+ni_);
  Cu[g]=cu; Ci[g]=ci; ninv[g]=nv; cnu[g]=cu*nv; cni[g]=ci*nv;
  cn8u[g] = f2f8(cu*nv*64.f);
  cn8i[g] = f2f8(ci*nv*64.f);
  // never-taken degenerate patch (all-masked group): set all valid bits
  if (fu){
    for (int k=0;k<1000;k++) Wb[(size_t)g*KP2B+k]=0xFF;
    for (int k=0;k<NU;k++)
      atomicOr((unsigned*)Wbt + (((size_t)k*GB8 + (g>>3))>>2), 1u<<((g&7) + 8*((g>>3)&3)));
  }
  if (fi){
    for (int k=1008;k<2258;k++) Wb[(size_t)g*KP2B+k]=0xFF;
    for (int k=8064;k<18064;k++)
      atomicOr((unsigned*)Wbt + (((size_t)k*GB8 + (g>>3))>>2), 1u<<((g&7) + 8*((g>>3)&3)));
  }
}

// ---------------- K6: fp8 GEMM with bit-expanded W operand, split-K to f32 slices ----------------
// MODE 0: gfsl[z] = expand(Wb).vt8^T, grid (32,1,16)
// MODE 1: tmpsl[z] = gfsT2_8.expand(Wbt)^T + u-row, grid (1,142,4)
// MODE 2: msgsl[z] = expand(Wb).tmpT8^T ; degsl = expand(Wb).u8, grid (32,1,16)
template<int MODE>
__global__ __launch_bounds__(256) void k_gemm(
    const unsigned char* __restrict__ A, const unsigned char* __restrict__ B,
    float* __restrict__ Cs, float* __restrict__ degsl,
    const unsigned char* __restrict__ u8,
    const unsigned char* __restrict__ cn8u, const unsigned char* __restrict__ cn8i,
    float* __restrict__ uslice, const unsigned char* __restrict__ rbsg,
    long ldF, long ldc)
{
  __shared__ __align__(16) unsigned char BufF[2][16384];  // fp8 operand tile (B for 0/2, A for 1)
  __shared__ __align__(16) unsigned char BufB[2][2048];   // bit tile [128][16]
  __shared__ __align__(16) unsigned char AuxR[2][1024];   // rbs k-chunk (MODE0/2)
  __shared__ unsigned int RowDw[128];                     // per-row value splat (MODE1)
  int t=threadIdx.x, wave=t>>6, lane=t&63;
  int I=blockIdx.x, J=blockIdx.y, z=blockIdx.z;
  int kt0=0, ktn=0;
  if (MODE==0){ kt0 = z*9; ktn = min(9, KT8-kt0); }
  else if (MODE==1){ kt0 = z*8; ktn = 8; }
  else {
    if (z<8){ kt0 = z*8;             ktn = min(8, UT8-kt0); }
    else    { kt0 = UT8 + (z-8)*10;  ktn = min(10, KT8-kt0); }
  }
  f32x4 acc[4][4];
  #pragma unroll
  for (int mi=0;mi<4;mi++)
    #pragma unroll
    for (int ni=0;ni<4;ni++){
      acc[mi][ni][0]=0.f; acc[mi][ni][1]=0.f; acc[mi][ni][2]=0.f; acc[mi][ni][3]=0.f;
    }
  f32x4 accd[4];
  if (MODE==2){
    #pragma unroll
    for (int mi=0;mi<4;mi++){ accd[mi][0]=0.f; accd[mi][1]=0.f; accd[mi][2]=0.f; accd[mi][3]=0.f; }
  }
  f32x4 accu[4];
  if (MODE==1){
    #pragma unroll
    for (int ni=0;ni<4;ni++){ accu[ni][0]=0.f; accu[ni][1]=0.f; accu[ni][2]=0.f; accu[ni][3]=0.f; }
  }
  int l7 = lane&7, q4 = lane>>4, cl15 = lane&15;
  int rowOff = wave*8 + (lane>>3);
  int cchunk = (lane&7) ^ ((lane>>3)&7);
  long aRow0 = (MODE==1) ? ((J>=UT8)?128:0) : 0;
  const unsigned char* Fbase;
  const unsigned char* Bitbase;
  if (MODE==1){ Fbase = A + aRow0*ldF + (long)cchunk*16; Bitbase = B + (long)J*128*GB8; }
  else        { Fbase = B + (long)cchunk*16;             Bitbase = A + (long)I*128*KP2B; }
  const unsigned char* cnrow = (MODE==1) ? ((J>=UT8) ? cn8i : cn8u) : nullptr;
  int mrow0 = (wave&1)*64, nrow0 = (wave>>1)*64;

  if (MODE==1 && t<128) RowDw[t] = 0x01010101u * (unsigned int)rbsg[(size_t)J*128 + t];

  auto STAGE = [&](int buf, int kt){
    long k0 = (long)kt*128;
    #pragma unroll
    for (int rr=0; rr<4; rr++)
      async16(BufF[buf] + wave*1024 + rr*4096, Fbase + (long)(rr*32 + rowOff)*ldF + k0);
    if (wave<2)
      async16(BufB[buf] + wave*1024, Bitbase + (long)(wave*64+lane)*(MODE==1?GB8:KP2B) + (long)kt*16);
    if (MODE!=1 && wave==2)
      async16(AuxR[buf], rbsg + (long)kt*128 + (long)(lane&7)*16);
  };

  STAGE(0, kt0);
  __syncthreads();

  for (int kt=kt0; kt<kt0+ktn; ++kt){
    int cur = (kt - kt0) & 1;
    if (kt+1 < kt0+ktn) STAGE(cur^1, kt+1);
    const unsigned char* Fb = BufF[cur];
    const unsigned char* Bb = BufB[cur];
    #pragma unroll
    for (int kk=0; kk<4; kk++){
      int xoff = (((kk*2 + (q4>>1)) ^ l7) << 4) + ((q4&1)<<3);
      int kb = kk*4 + q4;
      long af[4], bf[4];
      if (MODE==1){
        #pragma unroll
        for (int mi=0;mi<4;mi++)
          af[mi] = *(const long*)(Fb + (mrow0 + mi*16 + cl15)*128 + xoff);
        #pragma unroll
        for (int ni=0;ni<4;ni++){
          int row = nrow0 + ni*16 + cl15;
          unsigned int bb = Bb[row*16 + kb];
          unsigned int sp = RowDw[row];
          unsigned int lo = mask4(bb&15u)&sp, hi = mask4(bb>>4)&sp;
          bf[ni] = (long)(((unsigned long long)hi<<32)|(unsigned long long)lo);
        }
      } else {
        unsigned long long rdw = *(const unsigned long long*)(AuxR[cur] + kb*8);
        unsigned int rlo = (unsigned int)rdw, rhi = (unsigned int)(rdw>>32);
        #pragma unroll
        for (int mi=0;mi<4;mi++){
          unsigned int bb = Bb[(mrow0 + mi*16 + cl15)*16 + kb];
          unsigned int lo = mask4(bb&15u)&rlo, hi = mask4(bb>>4)&rhi;
          af[mi] = (long)(((unsigned long long)hi<<32)|(unsigned long long)lo);
        }
        #pragma unroll
        for (int ni=0;ni<4;ni++)
          bf[ni] = *(const long*)(Fb + (nrow0 + ni*16 + cl15)*128 + xoff);
      }
      #pragma unroll
      for (int mi=0;mi<4;mi++)
        #pragma unroll
        for (int ni=0;ni<4;ni++)
          acc[mi][ni] = __builtin_amdgcn_mfma_f32_16x16x32_fp8_fp8(af[mi], bf[ni], acc[mi][ni], 0,0,0);
      if (MODE==2){
        long bu = 0;
        if (cl15==0) bu = *(const long*)(u8 + (size_t)kt*128 + kk*32 + q4*8);
        #pragma unroll
        for (int mi=0;mi<4;mi++)
          accd[mi] = __builtin_amdgcn_mfma_f32_16x16x32_fp8_fp8(af[mi], bu, accd[mi], 0,0,0);
      }
      if (MODE==1){
        long au = 0;
        if (cl15==0) au = *(const long*)(cnrow + (size_t)kt*128 + kk*32 + q4*8);
        #pragma unroll
        for (int ni=0;ni<4;ni++)
          accu[ni] = __builtin_amdgcn_mfma_f32_16x16x32_fp8_fp8(au, bf[ni], accu[ni], 0,0,0);
      }
    }
    __syncthreads();
  }
  int cq = lane>>4, cl = lane&15;
  float* slice = (MODE==1) ? (Cs + (size_t)z*128*KP2) : (Cs + (size_t)z*G*128);
  #pragma unroll
  for (int mi=0;mi<4;mi++)
    #pragma unroll
    for (int ni=0;ni<4;ni++)
      #pragma unroll
      for (int rg=0;rg<4;rg++){
        int gi = (MODE==1 ? 0 : I*128) + mrow0 + mi*16 + cq*4 + rg;
        int hi = J*128 + nrow0 + ni*16 + cl;
        slice[(size_t)gi*ldc + hi] = acc[mi][ni][rg];
      }
  if (MODE==2 && (wave>>1)==0 && cl15==0){
    #pragma unroll
    for (int mi=0;mi<4;mi++)
      #pragma unroll
      for (int rg=0;rg<4;rg++){
        int gi = I*128 + mrow0 + mi*16 + cq*4 + rg;
        degsl[(size_t)z*G + gi] = accd[mi][rg];
      }
  }
  if (MODE==1 && (wave&1)==0 && q4==0){
    #pragma unroll
    for (int ni=0;ni<4;ni++){
      int si = J*128 + nrow0 + ni*16 + cl15;
      uslice[(size_t)z*KP2 + si] = accu[ni][0];
    }
  }
}

// ---------------- GFPOST: gf = (C_d/16)*sum_z gfsl ; gfsT2_8 both halves ----------------
__global__ __launch_bounds__(256) void k_gfpost(const float* __restrict__ gfsl,
    const float* __restrict__ Cu, const float* __restrict__ Ci, const float* __restrict__ ninv,
    float* __restrict__ gf, unsigned char* __restrict__ gfsT2_8)
{
  __shared__ float tile[64][65];
  int g0 = blockIdx.x*64, d0 = blockIdx.y*64;
  int tc=threadIdx.x&63, tr=threadIdx.x>>6;
  const float* Cd = blockIdx.y ? Ci : Cu;     // gf columns 64..127 are item-d
  #pragma unroll
  for (int i=0;i<16;i++){
    int rr=tr+i*4;
    size_t off = (size_t)(g0+rr)*128 + d0+tc;
    float s = 0.f;
    #pragma unroll
    for (int zz=0;zz<16;zz++) s += gfsl[(size_t)zz*G*128 + off];
    float gfv = s * Cd[g0+rr] * 0.0625f;
    gf[off] = gfv;
    tile[rr][tc] = gfv * ninv[g0+rr];
  }
  __syncthreads();
  #pragma unroll
  for (int i=0;i<16;i++){
    int dd=tr+i*4;
    float v = tile[tc][dd] * 64.f;
    int g = g0+tc;
    gfsT2_8[(size_t)(d0+dd)*G + g]     = f2f8(v*Cu[g]);
    gfsT2_8[(size_t)(128+d0+dd)*G + g] = f2f8(v*Ci[g]);
  }
}

// ---------------- R1: tmpT8 = fp8(sum_z tmpsl) ; u8 = fp8(sum_z uslice / 64) ----------------
__global__ __launch_bounds__(256) void k_red1(const float* __restrict__ tmpsl,
    unsigned char* __restrict__ tmpT8, const float* __restrict__ uslice, unsigned char* __restrict__ u8){
  int b = blockIdx.x, t = threadIdx.x;
  if (b >= 2272){
    int idx2 = (b-2272)*256 + t;
    if (idx2 < KP2/4){
      size_t off = (size_t)idx2*4;
      f32x4 s = *(const f32x4*)(uslice + off);
      #pragma unroll
      for (int z=1;z<4;z++){
        f32x4 v = *(const f32x4*)(uslice + (size_t)z*KP2 + off);
        s[0]+=v[0]; s[1]+=v[1]; s[2]+=v[2]; s[3]+=v[3];
      }
      uchar4 pk;
      pk.x = f2f8(s[0]*0.015625f);
      pk.y = f2f8(s[1]*0.015625f);
      pk.z = f2f8(s[2]*0.015625f);
      pk.w = f2f8(s[3]*0.015625f);
      *(uchar4*)(u8 + off) = pk;
    }
    return;
  }
  int idx = b*256 + t;
  int d = idx / 4544;
  int n = (idx - d*4544)*4;
  size_t off = (size_t)d*KP2 + n;
  f32x4 s = *(const f32x4*)(tmpsl + off);
  #pragma unroll
  for (int z=1;z<4;z++){
    f32x4 v = *(const f32x4*)(tmpsl + (size_t)z*128*KP2 + off);
    s[0]+=v[0]; s[1]+=v[1]; s[2]+=v[2]; s[3]+=v[3];
  }
  uchar4 pk;
  pk.x = f2f8(s[0]); pk.y = f2f8(s[1]); pk.z = f2f8(s[2]); pk.w = f2f8(s[3]);
  *(uchar4*)(tmpT8 + off) = pk;
}

// ---------------- K9 (absorbs red2): deg + msg-reduce + out = sigmoid(agg @ gW^T + gb) ----------------
__global__ __launch_bounds__(256) void k_final(const float* __restrict__ gf, const float* __restrict__ msgsl,
    const float* __restrict__ degsl, const float* __restrict__ cnu, const float* __restrict__ cni,
    const float* __restrict__ gW, const float* __restrict__ gb, float* __restrict__ out)
{
  __shared__ float Wl[64*129];
  __shared__ float aggL[4][128];
  __shared__ float gbL[64];
  __shared__ float degL[4];
  int t=threadIdx.x;
  for (int e=t; e<8192; e+=256){ int o=e>>7, dd=e&127; Wl[o*129+dd] = gW[e]; }
  if (t<64) gbL[t] = gb[t];
  int g0 = blockIdx.x*4;
  if (t<4){
    int g = g0+t;
    float su=0.f, si=0.f;
    #pragma unroll
    for (int z=0;z<8;z++) su += degsl[(size_t)z*G + g];
    #pragma unroll
    for (int z=8;z<16;z++) si += degsl[(size_t)z*G + g];
    degL[t] = cnu[g]*su + cni[g]*si;
  }
  __syncthreads();
  for (int e=t; e<512; e+=256){
    int gl=e>>7, dd=e&127; int g=g0+gl;
    size_t off = (size_t)g*128 + dd;
    float su=0.f, si=0.f;
    #pragma unroll
    for (int z=0;z<8;z++)  su += msgsl[(size_t)z*G*128 + off];
    #pragma unroll
    for (int z=8;z<16;z++) si += msgsl[(size_t)z*G*128 + off];
    float mv = (cnu[g]*su + cni[g]*si)*0.015625f;
    float dv = degL[gl];
    float hn = dv>0.f ? mv/dv : 0.f;
    aggL[gl][dd] = 0.8f*gf[off] + 0.2f*hn;
  }
  __syncthreads();
  int gl = t>>6, o = t&63;
  float s = gbL[o];
  #pragma unroll
  for (int dd=0; dd<128; dd++) s += aggL[gl][dd]*Wl[o*129+dd];
  out[(size_t)(g0+gl)*64 + o] = 1.f/(1.f+expf(-s));
}

extern "C" void kernel_launch(void* const* d_in, const int* in_sizes, int n_in,
                              void* d_out, int out_size, void* d_ws, size_t ws_size,
                              hipStream_t stream)
{
  (void)in_sizes; (void)n_in; (void)out_size; (void)ws_size;
  const int* H = (const int*)d_in[0];
  const float* feats = (const float*)d_in[1];
  const float* uWq=(const float*)d_in[3];
  const float* ubq=(const float*)d_in[4];
  const float* uWk=(const float*)d_in[5];
  const float* ubk=(const float*)d_in[6];
  const float* uWv=(const float*)d_in[7];
  const float* ubv=(const float*)d_in[8];
  const float* uWs=(const float*)d_in[9];
  const float* ubs=(const float*)d_in[10];
  const float* iWq=(const float*)d_in[11];
  const float* ibq=(const float*)d_in[12];
  const float* iWk=(const float*)d_in[13];
  const float* ibk=(const float*)d_in[14];
  const float* iWv=(const float*)d_in[15];
  const float* ibv=(const float*)d_in[16];
  const float* iWs=(const float*)d_in[17];
  const float* ibs=(const float*)d_in[18];
  const float* gW =(const float*)d_in[19];
  const float* gb =(const float*)d_in[20];
  float* out = (float*)d_out;

  char* p = (char*)d_ws;
  auto alloc=[&](size_t b)->void*{ void* r=(void*)p; p += (b+255)&~(size_t)255; return r; };
  // --- zero region (single small memset) ---
  char* zbase = p;
  float* suG  = (float*)alloc(130*4);
  float* Zu   = (float*)alloc(G*4);
  float* Zi   = (float*)alloc(G*4);
  float* S2u  = (float*)alloc(G*4);
  float* S2i  = (float*)alloc(G*4);
  unsigned char* vt8 = (unsigned char*)alloc((size_t)128*KP2);
  size_t zlen = (size_t)(p - zbase);
  // --- non-zeroed ---
  unsigned char* Wb    = (unsigned char*)alloc((size_t)G*KP2B);
  unsigned char* Wbt   = (unsigned char*)alloc((size_t)KP2*GB8);
  unsigned char* tmpT8 = (unsigned char*)alloc((size_t)128*KP2);
  unsigned char* gfsT2_8=(unsigned char*)alloc((size_t)256*G);
  // union slice buffer: gfsl (16 x G x 128 f32) / tmpsl (4 x 128 x KP2 f32) / msgsl (16 x G x 128 f32)
  float* slb  = (float*)alloc((size_t)4*128*KP2*4);
  float* uslice=(float*)alloc((size_t)4*KP2*4);
  float* degsl= (float*)alloc((size_t)16*G*4);
  float* gf   = (float*)alloc((size_t)G*128*4);
  unsigned short* vrow=(unsigned short*)alloc((size_t)NTOT*64*2);
  float* rfs  = (float*)alloc((size_t)KP2*4);
  unsigned char* rbs = (unsigned char*)alloc((size_t)KP2);
  float* Cu   = (float*)alloc(G*4);
  float* Ci   = (float*)alloc(G*4);
  float* cnu  = (float*)alloc(G*4);
  float* cni  = (float*)alloc(G*4);
  float* ninv = (float*)alloc(G*4);
  unsigned char* cn8u = (unsigned char*)alloc(G);
  unsigned char* cn8i = (unsigned char*)alloc(G);
  unsigned char* u8 = (unsigned char*)alloc((size_t)KP2);

  (void)hipMemsetAsync(zbase, 0, zlen, stream);

  k_proj<<<256,256,0,stream>>>(feats, uWv,ubv,uWs, iWv,ibv,iWs, vrow, suG);
  k_score<<<KP2/128,256,0,stream>>>(feats, suG, uWq,ubq,uWk,ubk,ubs,
                                    iWq,ibq,iWk,ibk,ibs, vrow, rfs, rbs, vt8);
  k_buildB<<<dim3(NSL128,32),256,0,stream>>>(H, rfs, Wb, Wbt, Zu, Zi, S2u, S2i);
  k_scales<<<16,256,0,stream>>>(Zu,Zi,S2u,S2i,Cu,Ci,cnu,cni,ninv,cn8u,cn8i,Wb,Wbt);
  // gf slices + reduce/transpose
  k_gemm<0><<<dim3(32,1,16),256,0,stream>>>(Wb, vt8, slb, nullptr, nullptr, nullptr, nullptr, nullptr,
                                            rbs, (long)KP2, 128);
  k_gfpost<<<dim3(64,2),256,0,stream>>>(slb, Cu, Ci, ninv, gf, gfsT2_8);
  // tmp slices (+ fused u-row) + fp8 reduce
  k_gemm<1><<<dim3(1,KT8,4),256,0,stream>>>(gfsT2_8, Wbt, slb, nullptr, nullptr, cn8u, cn8i, uslice,
                                            rbs, (long)G, (long)KP2);
  k_red1<<<2272+18,256,0,stream>>>(slb, tmpT8, uslice, u8);
  // msg/deg slices; reduce fused into k_final
  k_gemm<2><<<dim3(32,1,16),256,0,stream>>>(Wb, tmpT8, slb, degsl, u8, nullptr, nullptr, nullptr,
                                            rbs, (long)KP2, 128);
  k_final<<<G/4,256,0,stream>>>(gf, slb, degsl, cnu, cni, gW, gb, out);
}

// Round 7
// 662.545 us; speedup vs baseline: 2.7433x; 1.0075x over previous
//
#include <hip/hip_runtime.h>
#include <hip/hip_bf16.h>
#include <cstdint>
#include <cstddef>

#define NU   8000
#define NI   10000
#define NTOT 18000
#define G    4096
#define KP2  18176      // slots: users 0..8063, items 8064..18175
#define NSL128 142      // 128-slot tiles
#define KT8  142        // 128-byte k-tiles (K = KP2)
#define UT8  63         // user 128-tiles (63*128 = 8064)
#define KP2B 2272       // KP2/8 bit-bytes
#define GB8  512        // G/8 bit-bytes

typedef __attribute__((ext_vector_type(4))) float f32x4;

__device__ __forceinline__ float bfu(unsigned short u){
  return __uint_as_float(((unsigned)u)<<16);
}
__device__ __forceinline__ unsigned short f2b(float f){
  __hip_bfloat16 h = __float2bfloat16(f);
  return __builtin_bit_cast(unsigned short, h);
}
__device__ __forceinline__ unsigned char f2f8(float v){
  int p = __builtin_amdgcn_cvt_pk_fp8_f32(v, 0.f, 0, false);
  return (unsigned char)(p & 0xff);
}
template<int SEL>
__device__ __forceinline__ float f8tof(unsigned int w){
  return __builtin_amdgcn_cvt_f32_fp8((int)w, SEL);
}
__device__ __forceinline__ void async16(void* lds, const void* g){
  __builtin_amdgcn_global_load_lds((const __attribute__((address_space(1))) unsigned int*)g,
                                   (__attribute__((address_space(3))) unsigned int*)lds, 16, 0, 0);
}
__device__ __forceinline__ int slot2n(int s){
  return (s < 8064) ? (s < 8000 ? s : -1) : (s-64 < NTOT ? s-64 : -1);
}
// 4 bits -> dword byte-mask (0xFF per set bit). Exact, no LUT.
__device__ __forceinline__ unsigned int mask4(unsigned int n){
  return ((n*0x00204081u)&0x01010101u)*0xFFu;
}

// ---------------- K1: v projection only + su = Ws-weighted feats sum, sws = sum Ws ----------------
// (q/k eliminated: s[n] = w2.x[n] + c with w2,c derived from su/sws in k_score)
__global__ __launch_bounds__(256) void k_proj(
    const float* __restrict__ feats,
    const float* uWv, const float* ubv, const float* uWs,
    const float* iWv, const float* ibv, const float* iWs,
    unsigned short* __restrict__ vrow, float* __restrict__ suG)
{
  __shared__ unsigned short Wt[2*4096];
  __shared__ float bl[2*64];
  __shared__ float sacc[130];
  const float* mats[2]  = {uWv,iWv};
  const float* bias2[2] = {ubv,ibv};
  int t = threadIdx.x;
  for (int m=0;m<2;m++)
    for (int e=t; e<4096; e+=256){
      int dd = e>>6, jj = e&63;
      Wt[m*4096 + jj*64 + dd] = f2b(mats[m][e]);
    }
  for (int e=t; e<128; e+=256) bl[e] = bias2[e>>6][e&63];
  if (t<130) sacc[t]=0.f;
  __syncthreads();
  int wave=t>>6, lane=t&63;
  int gw = blockIdx.x*4+wave, nw = gridDim.x*4;
  float accU=0.f, accI=0.f, swsU=0.f, swsI=0.f;
  for (int n=gw; n<NTOT; n+=nw){
    int br = (n>=NU);
    const unsigned short* W = Wt + br*4096;
    float x = feats[(size_t)n*64+lane];
    float vd = bl[br*64+lane];
    #pragma unroll 16
    for (int j=0;j<64;j++){
      float xj = __shfl(x, j, 64);
      vd += xj * bfu(W[j*64+lane]);
    }
    vrow[(size_t)n*64+lane] = f2b(vd);
    float wsn = br ? iWs[n-NU] : uWs[n];
    if (br){ accI += wsn*x; swsI += wsn; } else { accU += wsn*x; swsU += wsn; }
  }
  atomicAdd(&sacc[lane], accU);
  atomicAdd(&sacc[64+lane], accI);
  if (lane==0){ atomicAdd(&sacc[128], swsU); atomicAdd(&sacc[129], swsI); }
  __syncthreads();
  if (t<130) atomicAdd(&suG[t], sacc[t]);
}

// ---------------- K2: w2 derivation (redundant per block) + scores + vt8 build ----------------
__global__ __launch_bounds__(256) void k_score(
    const float* __restrict__ feats, const float* __restrict__ suG,
    const float* uWq, const float* ubq, const float* uWk, const float* ubk, const float* ubs,
    const float* iWq, const float* ibq, const float* iWk, const float* ibk, const float* ibs,
    const unsigned short* __restrict__ vrow,
    unsigned char* __restrict__ rbs, unsigned char* __restrict__ vt8)
{
  __shared__ float suL[130];
  __shared__ float wskL[128];
  __shared__ float w2L[128];
  __shared__ float cL[2];
  __shared__ unsigned short tile[64][65];
  int t=threadIdx.x, wave=t>>6, lane=t&63;
  if (t<130) suL[t]=suG[t];
  __syncthreads();
  // wsk[d] = sum_j su[j]*Wk[d][j] + sws*bk[d]
  if (wave<2){
    const float* Wk = wave? iWk : uWk;
    const float* bk = wave? ibk : ubk;
    const float* su = suL + wave*64;
    float a = suL[128+wave]*bk[lane];
    #pragma unroll 8
    for (int j=0;j<64;j++) a += su[j]*Wk[lane*64+j];
    wskL[wave*64+lane] = a;
  }
  __syncthreads();
  // w2[j] = sum_d wsk[d]*Wq[d][j] ; c = wsk.bq + bs
  if (wave<2){
    const float* Wq = wave? iWq : uWq;
    const float* bq = wave? ibq : ubq;
    const float* wk = wskL + wave*64;
    float a = 0.f;
    #pragma unroll 8
    for (int d=0; d<64; d++) a += wk[d]*Wq[(size_t)d*64+lane];
    w2L[wave*64+lane] = a;
    float cp = wk[lane]*bq[lane];
    #pragma unroll
    for (int m=32;m>=1;m>>=1) cp += __shfl_xor(cp, m, 64);
    if (lane==0) cL[wave] = cp + (wave? ibs[0] : ubs[0]);
  }
  __syncthreads();
  int s0 = blockIdx.x*128;
  int br = (s0>=8064);
  // scores: s[n] = w2 . feats[n] + c
  #pragma unroll 4
  for (int i=0;i<32;i++){
    int slot = s0 + i*4 + wave;
    int n = slot2n(slot);
    float v = 0.f;
    if (n>=0) v = feats[(size_t)n*64+lane] * w2L[br*64+lane];
    #pragma unroll
    for (int m=32;m>=1;m>>=1) v += __shfl_xor(v, m, 64);
    if (lane==0){
      if (n>=0){
        rbs[slot] = f2f8(expf(v + cL[br]));
      } else { rbs[slot]=0; }
    }
  }
  // vt8 for this block's two 64-slot tiles (columns outside own side stay memset-zero)
  int dOff = br ? 64 : 0;
  int tc = t&63, tr = t>>6;
  for (int h=0; h<2; h++){
    int sb = s0 + h*64;
    __syncthreads();
    #pragma unroll
    for (int i=0;i<16;i++){
      int row = tr+i*4;
      int n = slot2n(sb+row);
      tile[row][tc] = (n>=0) ? vrow[(size_t)n*64+tc] : (unsigned short)0;
    }
    __syncthreads();
    #pragma unroll
    for (int i=0;i<16;i++){
      int dd = tr+i*4;
      float v = bfu(tile[tc][dd]) * 16.f;
      vt8[(size_t)(dOff+dd)*KP2 + sb+tc] = f2f8(v);
    }
  }
}

// ---------------- K3: ONE pass over H -> bit matrices Wb, Wbt + Z, S2 (NO fence, NO tail) ----------------
__global__ __launch_bounds__(256) void k_buildB(
    const int* __restrict__ H, const unsigned char* __restrict__ rbs,
    unsigned char* __restrict__ Wb, unsigned char* __restrict__ Wbt,
    float* __restrict__ Zu, float* __restrict__ Zi,
    float* __restrict__ S2u, float* __restrict__ S2i)
{
  __shared__ __align__(16) unsigned char Bt[128][16];  // bit tile
  __shared__ float rl[128];
  __shared__ float zp[16][128];
  __shared__ float sp[16][128];
  int t = threadIdx.x;
  int s0 = blockIdx.x*128, g0 = blockIdx.y*128;
  int isItem = (s0 >= 8064);
  if (t<128){
    int n = slot2n(s0+t);
    rl[t] = (n>=0)? f8tof<0>((unsigned int)rbs[s0+t]) : 0.f;   // == old rfs, bit-identical
  }
  __syncthreads();
  int gb = t&15, rbase = t>>4;
  float za[8]={0.f,0.f,0.f,0.f,0.f,0.f,0.f,0.f};
  float sa[8]={0.f,0.f,0.f,0.f,0.f,0.f,0.f,0.f};
  #pragma unroll
  for (int i=0;i<8;i++){
    int row = rbase + i*16;
    int n = slot2n(s0+row);
    unsigned int b8 = 0;
    if (n>=0){
      const int* hp = H + (size_t)n*G + g0 + gb*8;
      int4 h0 = *(const int4*)hp;
      int4 h1 = *(const int4*)(hp+4);
      float rq = rl[row], rq2 = rq*rq;
      if (h0.x){ b8|=1u;    za[0]+=rq; sa[0]+=rq2; }
      if (h0.y){ b8|=2u;    za[1]+=rq; sa[1]+=rq2; }
      if (h0.z){ b8|=4u;    za[2]+=rq; sa[2]+=rq2; }
      if (h0.w){ b8|=8u;    za[3]+=rq; sa[3]+=rq2; }
      if (h1.x){ b8|=16u;   za[4]+=rq; sa[4]+=rq2; }
      if (h1.y){ b8|=32u;   za[5]+=rq; sa[5]+=rq2; }
      if (h1.z){ b8|=64u;   za[6]+=rq; sa[6]+=rq2; }
      if (h1.w){ b8|=128u;  za[7]+=rq; sa[7]+=rq2; }
    }
    Bt[row][gb] = (unsigned char)b8;
  }
  #pragma unroll
  for (int j=0;j<8;j++){ zp[rbase][gb*8+j]=za[j]; sp[rbase][gb*8+j]=sa[j]; }
  __syncthreads();
  // Wbt rows: 8B/thread
  {
    int row = t>>1, half = t&1;
    *(unsigned long long*)(Wbt + (size_t)(s0+row)*GB8 + (g0>>3) + half*8) =
        *(const unsigned long long*)(&Bt[row][half*8]);
  }
  // Wb transpose: 8 output bytes per thread
  {
    int g = t>>1, sh = t&1;
    int gB = g>>3, gs = g&7;
    unsigned long long ob = 0;
    #pragma unroll
    for (int sb=0; sb<8; sb++){
      int base = (sh*8+sb)*8;
      unsigned int x = 0;
      #pragma unroll
      for (int j=0;j<8;j++) x |= (((unsigned int)(Bt[base+j][gB]) >> gs)&1u) << j;
      ob |= (unsigned long long)x << (sb*8);
    }
    *(unsigned long long*)(Wb + (size_t)(g0+g)*KP2B + (s0>>3) + sh*8) = ob;
  }
  if (t<128){
    float z=0.f, s2=0.f;
    #pragma unroll
    for (int j=0;j<16;j++){ z += zp[j][t]; s2 += sp[j][t]; }
    if (isItem){ atomicAdd(&Zi[g0+t], z); atomicAdd(&S2i[g0+t], s2); }
    else       { atomicAdd(&Zu[g0+t], z); atomicAdd(&S2u[g0+t], s2); }
  }
}

// ---------------- K6: fp8 GEMM with bit-expanded W operand, split-K to f32 slices ----------------
// MODE 0: gfsl[z] = expand(Wb).vt8^T, grid (32,1,16)
// MODE 1: tmpsl[z] = gfsT2_8.expand(Wbt)^T + u-row, grid (1,142,4)
// MODE 2: msgsl[z] = expand(Wb).tmpT8^T ; degsl = expand(Wb).u8, grid (32,1,16)
template<int MODE>
__global__ __launch_bounds__(256) void k_gemm(
    const unsigned char* __restrict__ A, const unsigned char* __restrict__ B,
    float* __restrict__ Cs, float* __restrict__ degsl,
    const unsigned char* __restrict__ u8,
    const unsigned char* __restrict__ cn8u, const unsigned char* __restrict__ cn8i,
    float* __restrict__ uslice, const unsigned char* __restrict__ rbsg,
    long ldF, long ldc)
{
  __shared__ __align__(16) unsigned char BufF[2][16384];  // fp8 operand tile (B for 0/2, A for 1)
  __shared__ __align__(16) unsigned char BufB[2][2048];   // bit tile [128][16]
  __shared__ __align__(16) unsigned char AuxR[2][1024];   // rbs k-chunk (MODE0/2)
  __shared__ unsigned int RowDw[128];                     // per-row value splat (MODE1)
  int t=threadIdx.x, wave=t>>6, lane=t&63;
  int I=blockIdx.x, J=blockIdx.y, z=blockIdx.z;
  int kt0=0, ktn=0;
  if (MODE==0){ kt0 = z*9; ktn = min(9, KT8-kt0); }
  else if (MODE==1){ kt0 = z*8; ktn = 8; }
  else {
    if (z<8){ kt0 = z*8;             ktn = min(8, UT8-kt0); }
    else    { kt0 = UT8 + (z-8)*10;  ktn = min(10, KT8-kt0); }
  }
  f32x4 acc[4][4];
  #pragma unroll
  for (int mi=0;mi<4;mi++)
    #pragma unroll
    for (int ni=0;ni<4;ni++){
      acc[mi][ni][0]=0.f; acc[mi][ni][1]=0.f; acc[mi][ni][2]=0.f; acc[mi][ni][3]=0.f;
    }
  f32x4 accd[4];
  if (MODE==2){
    #pragma unroll
    for (int mi=0;mi<4;mi++){ accd[mi][0]=0.f; accd[mi][1]=0.f; accd[mi][2]=0.f; accd[mi][3]=0.f; }
  }
  f32x4 accu[4];
  if (MODE==1){
    #pragma unroll
    for (int ni=0;ni<4;ni++){ accu[ni][0]=0.f; accu[ni][1]=0.f; accu[ni][2]=0.f; accu[ni][3]=0.f; }
  }
  int l7 = lane&7, q4 = lane>>4, cl15 = lane&15;
  int rowOff = wave*8 + (lane>>3);
  int cchunk = (lane&7) ^ ((lane>>3)&7);
  long aRow0 = (MODE==1) ? ((J>=UT8)?128:0) : 0;
  const unsigned char* Fbase;
  const unsigned char* Bitbase;
  if (MODE==1){ Fbase = A + aRow0*ldF + (long)cchunk*16; Bitbase = B + (long)J*128*GB8; }
  else        { Fbase = B + (long)cchunk*16;             Bitbase = A + (long)I*128*KP2B; }
  const unsigned char* cnrow = (MODE==1) ? ((J>=UT8) ? cn8i : cn8u) : nullptr;
  int mrow0 = (wave&1)*64, nrow0 = (wave>>1)*64;

  if (MODE==1 && t<128) RowDw[t] = 0x01010101u * (unsigned int)rbsg[(size_t)J*128 + t];

  auto STAGE = [&](int buf, int kt){
    long k0 = (long)kt*128;
    #pragma unroll
    for (int rr=0; rr<4; rr++)
      async16(BufF[buf] + wave*1024 + rr*4096, Fbase + (long)(rr*32 + rowOff)*ldF + k0);
    if (wave<2)
      async16(BufB[buf] + wave*1024, Bitbase + (long)(wave*64+lane)*(MODE==1?GB8:KP2B) + (long)kt*16);
    if (MODE!=1 && wave==2)
      async16(AuxR[buf], rbsg + (long)kt*128 + (long)(lane&7)*16);
  };

  STAGE(0, kt0);
  __syncthreads();

  for (int kt=kt0; kt<kt0+ktn; ++kt){
    int cur = (kt - kt0) & 1;
    if (kt+1 < kt0+ktn) STAGE(cur^1, kt+1);
    const unsigned char* Fb = BufF[cur];
    const unsigned char* Bb = BufB[cur];
    #pragma unroll
    for (int kk=0; kk<4; kk++){
      int xoff = (((kk*2 + (q4>>1)) ^ l7) << 4) + ((q4&1)<<3);
      int kb = kk*4 + q4;
      long af[4], bf[4];
      if (MODE==1){
        #pragma unroll
        for (int mi=0;mi<4;mi++)
          af[mi] = *(const long*)(Fb + (mrow0 + mi*16 + cl15)*128 + xoff);
        #pragma unroll
        for (int ni=0;ni<4;ni++){
          int row = nrow0 + ni*16 + cl15;
          unsigned int bb = Bb[row*16 + kb];
          unsigned int sp = RowDw[row];
          unsigned int lo = mask4(bb&15u)&sp, hi = mask4(bb>>4)&sp;
          bf[ni] = (long)(((unsigned long long)hi<<32)|(unsigned long long)lo);
        }
      } else {
        unsigned long long rdw = *(const unsigned long long*)(AuxR[cur] + kb*8);
        unsigned int rlo = (unsigned int)rdw, rhi = (unsigned int)(rdw>>32);
        #pragma unroll
        for (int mi=0;mi<4;mi++){
          unsigned int bb = Bb[(mrow0 + mi*16 + cl15)*16 + kb];
          unsigned int lo = mask4(bb&15u)&rlo, hi = mask4(bb>>4)&rhi;
          af[mi] = (long)(((unsigned long long)hi<<32)|(unsigned long long)lo);
        }
        #pragma unroll
        for (int ni=0;ni<4;ni++)
          bf[ni] = *(const long*)(Fb + (nrow0 + ni*16 + cl15)*128 + xoff);
      }
      #pragma unroll
      for (int mi=0;mi<4;mi++)
        #pragma unroll
        for (int ni=0;ni<4;ni++)
          acc[mi][ni] = __builtin_amdgcn_mfma_f32_16x16x32_fp8_fp8(af[mi], bf[ni], acc[mi][ni], 0,0,0);
      if (MODE==2){
        long bu = 0;
        if (cl15==0) bu = *(const long*)(u8 + (size_t)kt*128 + kk*32 + q4*8);
        #pragma unroll
        for (int mi=0;mi<4;mi++)
          accd[mi] = __builtin_amdgcn_mfma_f32_16x16x32_fp8_fp8(af[mi], bu, accd[mi], 0,0,0);
      }
      if (MODE==1){
        long au = 0;
        if (cl15==0) au = *(const long*)(cnrow + (size_t)kt*128 + kk*32 + q4*8);
        #pragma unroll
        for (int ni=0;ni<4;ni++)
          accu[ni] = __builtin_amdgcn_mfma_f32_16x16x32_fp8_fp8(au, bf[ni], accu[ni], 0,0,0);
      }
    }
    __syncthreads();
  }
  int cq = lane>>4, cl = lane&15;
  float* slice = (MODE==1) ? (Cs + (size_t)z*128*KP2) : (Cs + (size_t)z*G*128);
  #pragma unroll
  for (int mi=0;mi<4;mi++)
    #pragma unroll
    for (int ni=0;ni<4;ni++)
      #pragma unroll
      for (int rg=0;rg<4;rg++){
        int gi = (MODE==1 ? 0 : I*128) + mrow0 + mi*16 + cq*4 + rg;
        int hi = J*128 + nrow0 + ni*16 + cl;
        slice[(size_t)gi*ldc + hi] = acc[mi][ni][rg];
      }
  if (MODE==2 && (wave>>1)==0 && cl15==0){
    #pragma unroll
    for (int mi=0;mi<4;mi++)
      #pragma unroll
      for (int rg=0;rg<4;rg++){
        int gi = I*128 + mrow0 + mi*16 + cq*4 + rg;
        degsl[(size_t)z*G + gi] = accd[mi][rg];
      }
  }
  if (MODE==1 && (wave&1)==0 && q4==0){
    #pragma unroll
    for (int ni=0;ni<4;ni++){
      int si = J*128 + nrow0 + ni*16 + cl15;
      uslice[(size_t)z*KP2 + si] = accu[ni][0];
    }
  }
}

// ---------------- GFPOST (absorbs scales): per-block local cu/ci/nv from Z/S2;
// gf = (C_d/16)*sum_z gfsl ; gfsT2_8 both halves; y==0 writes cnu/cni/cn8u/cn8i ----------------
__global__ __launch_bounds__(256) void k_gfpost(const float* __restrict__ gfsl,
    const float* __restrict__ Zu, const float* __restrict__ Zi,
    const float* __restrict__ S2u, const float* __restrict__ S2i,
    float* __restrict__ cnu, float* __restrict__ cni,
    unsigned char* __restrict__ cn8u, unsigned char* __restrict__ cn8i,
    float* __restrict__ gf, unsigned char* __restrict__ gfsT2_8)
{
  __shared__ float tile[64][65];
  __shared__ float cuL[64], ciL[64], nvL[64];
  int g0 = blockIdx.x*64, d0 = blockIdx.y*64;
  int t = threadIdx.x;
  if (t < 64){
    int g = g0 + t;
    float zu=Zu[g], zi=Zi[g];
    int fu = !(zu>0.f), fi = !(zi>0.f);
    float cu = fu ? (1.f/(float)NU) : 1.f/zu;
    float ci = fi ? (1.f/(float)NI) : 1.f/zi;
    float nu  = fu ? (1.f/(float)NU) : S2u[g]*cu*cu;
    float ni_ = fi ? (1.f/(float)NI) : S2i[g]*ci*ci;
    float nv = rsqrtf(nu+ni_);
    cuL[t]=cu; ciL[t]=ci; nvL[t]=nv;
    if (blockIdx.y==0){
      cnu[g]=cu*nv; cni[g]=ci*nv;
      cn8u[g] = f2f8(cu*nv*64.f);
      cn8i[g] = f2f8(ci*nv*64.f);
    }
  }
  __syncthreads();
  int tc=t&63, tr=t>>6;
  int isI = blockIdx.y;            // gf columns 64..127 are item-derived
  #pragma unroll
  for (int i=0;i<16;i++){
    int rr=tr+i*4;
    size_t off = (size_t)(g0+rr)*128 + d0+tc;
    float s = 0.f;
    #pragma unroll
    for (int zz=0;zz<16;zz++) s += gfsl[(size_t)zz*G*128 + off];
    float gfv = s * (isI ? ciL[rr] : cuL[rr]) * 0.0625f;
    gf[off] = gfv;
    tile[rr][tc] = gfv * nvL[rr];
  }
  __syncthreads();
  #pragma unroll
  for (int i=0;i<16;i++){
    int dd=tr+i*4;
    float v = tile[tc][dd] * 64.f;
    gfsT2_8[(size_t)(d0+dd)*G + g0+tc]     = f2f8(v*cuL[tc]);
    gfsT2_8[(size_t)(128+d0+dd)*G + g0+tc] = f2f8(v*ciL[tc]);
  }
}

// ---------------- R1: tmpT8 = fp8(sum_z tmpsl) ; u8 = fp8(sum_z uslice / 64) ----------------
__global__ __launch_bounds__(256) void k_red1(const float* __restrict__ tmpsl,
    unsigned char* __restrict__ tmpT8, const float* __restrict__ uslice, unsigned char* __restrict__ u8){
  int b = blockIdx.x, t = threadIdx.x;
  if (b >= 2272){
    int idx2 = (b-2272)*256 + t;
    if (idx2 < KP2/4){
      size_t off = (size_t)idx2*4;
      f32x4 s = *(const f32x4*)(uslice + off);
      #pragma unroll
      for (int z=1;z<4;z++){
        f32x4 v = *(const f32x4*)(uslice + (size_t)z*KP2 + off);
        s[0]+=v[0]; s[1]+=v[1]; s[2]+=v[2]; s[3]+=v[3];
      }
      uchar4 pk;
      pk.x = f2f8(s[0]*0.015625f);
      pk.y = f2f8(s[1]*0.015625f);
      pk.z = f2f8(s[2]*0.015625f);
      pk.w = f2f8(s[3]*0.015625f);
      *(uchar4*)(u8 + off) = pk;
    }
    return;
  }
  int idx = b*256 + t;
  int d = idx / 4544;
  int n = (idx - d*4544)*4;
  size_t off = (size_t)d*KP2 + n;
  f32x4 s = *(const f32x4*)(tmpsl + off);
  #pragma unroll
  for (int z=1;z<4;z++){
    f32x4 v = *(const f32x4*)(tmpsl + (size_t)z*128*KP2 + off);
    s[0]+=v[0]; s[1]+=v[1]; s[2]+=v[2]; s[3]+=v[3];
  }
  uchar4 pk;
  pk.x = f2f8(s[0]); pk.y = f2f8(s[1]); pk.z = f2f8(s[2]); pk.w = f2f8(s[3]);
  *(uchar4*)(tmpT8 + off) = pk;
}

// ---------------- K9 (absorbs red2): deg + msg-reduce + out = sigmoid(agg @ gW^T + gb) ----------------
__global__ __launch_bounds__(256) void k_final(const float* __restrict__ gf, const float* __restrict__ msgsl,
    const float* __restrict__ degsl, const float* __restrict__ cnu, const float* __restrict__ cni,
    const float* __restrict__ gW, const float* __restrict__ gb, float* __restrict__ out)
{
  __shared__ float Wl[64*129];
  __shared__ float aggL[4][128];
  __shared__ float gbL[64];
  __shared__ float degL[4];
  int t=threadIdx.x;
  for (int e=t; e<8192; e+=256){ int o=e>>7, dd=e&127; Wl[o*129+dd] = gW[e]; }
  if (t<64) gbL[t] = gb[t];
  int g0 = blockIdx.x*4;
  if (t<4){
    int g = g0+t;
    float su=0.f, si=0.f;
    #pragma unroll
    for (int z=0;z<8;z++) su += degsl[(size_t)z*G + g];
    #pragma unroll
    for (int z=8;z<16;z++) si += degsl[(size_t)z*G + g];
    degL[t] = cnu[g]*su + cni[g]*si;
  }
  __syncthreads();
  for (int e=t; e<512; e+=256){
    int gl=e>>7, dd=e&127; int g=g0+gl;
    size_t off = (size_t)g*128 + dd;
    float su=0.f, si=0.f;
    #pragma unroll
    for (int z=0;z<8;z++)  su += msgsl[(size_t)z*G*128 + off];
    #pragma unroll
    for (int z=8;z<16;z++) si += msgsl[(size_t)z*G*128 + off];
    float mv = (cnu[g]*su + cni[g]*si)*0.015625f;
    float dv = degL[gl];
    float hn = dv>0.f ? mv/dv : 0.f;
    aggL[gl][dd] = 0.8f*gf[off] + 0.2f*hn;
  }
  __syncthreads();
  int gl = t>>6, o = t&63;
  float s = gbL[o];
  #pragma unroll
  for (int dd=0; dd<128; dd++) s += aggL[gl][dd]*Wl[o*129+dd];
  out[(size_t)(g0+gl)*64 + o] = 1.f/(1.f+expf(-s));
}

extern "C" void kernel_launch(void* const* d_in, const int* in_sizes, int n_in,
                              void* d_out, int out_size, void* d_ws, size_t ws_size,
                              hipStream_t stream)
{
  (void)in_sizes; (void)n_in; (void)out_size; (void)ws_size;
  const int* H = (const int*)d_in[0];
  const float* feats = (const float*)d_in[1];
  const float* uWq=(const float*)d_in[3];
  const float* ubq=(const float*)d_in[4];
  const float* uWk=(const float*)d_in[5];
  const float* ubk=(const float*)d_in[6];
  const float* uWv=(const float*)d_in[7];
  const float* ubv=(const float*)d_in[8];
  const float* uWs=(const float*)d_in[9];
  const float* ubs=(const float*)d_in[10];
  const float* iWq=(const float*)d_in[11];
  const float* ibq=(const float*)d_in[12];
  const float* iWk=(const float*)d_in[13];
  const float* ibk=(const float*)d_in[14];
  const float* iWv=(const float*)d_in[15];
  const float* ibv=(const float*)d_in[16];
  const float* iWs=(const float*)d_in[17];
  const float* ibs=(const float*)d_in[18];
  const float* gW =(const float*)d_in[19];
  const float* gb =(const float*)d_in[20];
  float* out = (float*)d_out;

  char* p = (char*)d_ws;
  auto alloc=[&](size_t b)->void*{ void* r=(void*)p; p += (b+255)&~(size_t)255; return r; };
  // --- zero region (single small memset) ---
  char* zbase = p;
  float* suG  = (float*)alloc(130*4);
  float* Zu   = (float*)alloc(G*4);
  float* Zi   = (float*)alloc(G*4);
  float* S2u  = (float*)alloc(G*4);
  float* S2i  = (float*)alloc(G*4);
  unsigned char* vt8 = (unsigned char*)alloc((size_t)128*KP2);
  size_t zlen = (size_t)(p - zbase);
  // --- non-zeroed ---
  unsigned char* Wb    = (unsigned char*)alloc((size_t)G*KP2B);
  unsigned char* Wbt   = (unsigned char*)alloc((size_t)KP2*GB8);
  unsigned char* tmpT8 = (unsigned char*)alloc((size_t)128*KP2);
  unsigned char* gfsT2_8=(unsigned char*)alloc((size_t)256*G);
  // union slice buffer: gfsl (16 x G x 128 f32) / tmpsl (4 x 128 x KP2 f32) / msgsl (16 x G x 128 f32)
  float* slb  = (float*)alloc((size_t)4*128*KP2*4);
  float* uslice=(float*)alloc((size_t)4*KP2*4);
  float* degsl= (float*)alloc((size_t)16*G*4);
  float* gf   = (float*)alloc((size_t)G*128*4);
  unsigned short* vrow=(unsigned short*)alloc((size_t)NTOT*64*2);
  unsigned char* rbs = (unsigned char*)alloc((size_t)KP2);
  float* cnu  = (float*)alloc(G*4);
  float* cni  = (float*)alloc(G*4);
  unsigned char* cn8u = (unsigned char*)alloc(G);
  unsigned char* cn8i = (unsigned char*)alloc(G);
  unsigned char* u8 = (unsigned char*)alloc((size_t)KP2);

  (void)hipMemsetAsync(zbase, 0, zlen, stream);

  k_proj<<<256,256,0,stream>>>(feats, uWv,ubv,uWs, iWv,ibv,iWs, vrow, suG);
  k_score<<<KP2/128,256,0,stream>>>(feats, suG, uWq,ubq,uWk,ubk,ubs,
                                    iWq,ibq,iWk,ibk,ibs, vrow, rbs, vt8);
  k_buildB<<<dim3(NSL128,32),256,0,stream>>>(H, rbs, Wb, Wbt, Zu, Zi, S2u, S2i);
  // gf slices
  k_gemm<0><<<dim3(32,1,16),256,0,stream>>>(Wb, vt8, slb, nullptr, nullptr, nullptr, nullptr, nullptr,
                                            rbs, (long)KP2, 128);
  // fused scales + reduce/transpose
  k_gfpost<<<dim3(64,2),256,0,stream>>>(slb, Zu, Zi, S2u, S2i, cnu, cni, cn8u, cn8i, gf, gfsT2_8);
  // tmp slices (+ fused u-row) + fp8 reduce
  k_gemm<1><<<dim3(1,KT8,4),256,0,stream>>>(gfsT2_8, Wbt, slb, nullptr, nullptr, cn8u, cn8i, uslice,
                                            rbs, (long)G, (long)KP2);
  k_red1<<<2272+18,256,0,stream>>>(slb, tmpT8, uslice, u8);
  // msg/deg slices; reduce fused into k_final
  k_gemm<2><<<dim3(32,1,16),256,0,stream>>>(Wb, tmpT8, slb, degsl, u8, nullptr, nullptr, nullptr,
                                            rbs, (long)KP2, 128);
  k_final<<<G/4,256,0,stream>>>(gf, slb, degsl, cnu, cni, gW, gb, out);
}